// Round 2
// baseline (5761.098 us; speedup 1.0000x reference)
//
#include <hip/hip_runtime.h>
#include <hip/hip_bf16.h>
#include <cstdint>
#include <type_traits>

// Problem constants (B,N,D,H) = (32,1024,512,8). Inputs/outputs fp32;
// compute in bf16 MFMA (2%-relative threshold admits it).
constexpr int B_SZ = 32;
constexpr int N_SZ = 1024;
constexpr int D_SZ = 512;
constexpr int H_SZ = 8;
constexpr int HD   = H_SZ * D_SZ;   // 4096

typedef __attribute__((ext_vector_type(8))) short short8;   // 8 x bf16 (4 VGPRs)
typedef __attribute__((ext_vector_type(4))) float floatx4;  // MFMA acc
typedef unsigned short u16;

static __device__ __forceinline__ u16 f2bf(float f) {
    union { float f; unsigned int i; } c; c.f = f;
    unsigned int x = c.i;
    unsigned int r = x + 0x7FFFu + ((x >> 16) & 1u);  // RNE
    return (u16)(r >> 16);
}

// ---------------------------------------------------------------------------
// fp32 -> bf16 elementwise (weights). n must be multiple of 1024.
// ---------------------------------------------------------------------------
__global__ void cvt_kernel(const float* __restrict__ src, u16* __restrict__ dst) {
    int idx = (blockIdx.x * 256 + threadIdx.x) * 4;
    float4 v = *(const float4*)(src + idx);
    ushort4 o;
    o.x = f2bf(v.x); o.y = f2bf(v.y); o.z = f2bf(v.z); o.w = f2bf(v.w);
    *(ushort4*)(dst + idx) = o;
}

// ---------------------------------------------------------------------------
// Permute+convert Wo: Wp[e][h*D+d] = bf16(Wo[e][d*H+h])
// (attention writes its output as [b,n,h*D+d], so Wo columns must match)
// ---------------------------------------------------------------------------
__global__ void woperm_kernel(const float* __restrict__ Wo, u16* __restrict__ Wp) {
    int idx = blockIdx.x * 256 + threadIdx.x;      // over 512*4096
    int e = idx >> 12;
    int c = idx & 4095;
    int d  = c & 511;
    int hh = c >> 9;
    Wp[idx] = f2bf(Wo[((size_t)e << 12) + d * H_SZ + hh]);
}

// ---------------------------------------------------------------------------
// GEMM: C[M,Nc] = A[M,K] @ W[Nc,K]^T + bias[Nc].
// A: fp32 (converted during staging) or bf16. W: bf16. C: bf16 or fp32.
// 128x128 tile, BK=32, 256 threads (2x2 waves, each 64x64 = 4x4 mfma tiles).
// ---------------------------------------------------------------------------
template<typename AT, typename CT>
__global__ __launch_bounds__(256, 2)
void gemm_bt(const AT* __restrict__ A, const u16* __restrict__ W,
             const float* __restrict__ bias, CT* __restrict__ C,
             int M, int Nc, int K)
{
    __shared__ u16 Alds[128 * 40];
    __shared__ u16 Blds[128 * 40];
    const int tid  = threadIdx.x;
    const int lane = tid & 63;
    const int wave = tid >> 6;
    const int wm = wave >> 1, wn = wave & 1;
    const int m16 = lane & 15, quad = lane >> 4;
    const size_t tm0 = (size_t)blockIdx.x * 128;
    const size_t tn0 = (size_t)blockIdx.y * 128;

    floatx4 acc[4][4];
#pragma unroll
    for (int i = 0; i < 4; i++)
#pragma unroll
        for (int j = 0; j < 4; j++) acc[i][j] = (floatx4){0.f, 0.f, 0.f, 0.f};

    const int srow  = tid >> 1;          // 0..127
    const int skoff = (tid & 1) * 16;    // 0 or 16 elems
    const AT*  ag = A + (tm0 + srow) * (size_t)K + skoff;
    const u16* bg = W + (tn0 + srow) * (size_t)K + skoff;

    for (int k0 = 0; k0 < K; k0 += 32) {
        short8 a0, a1;
        if constexpr (std::is_same_v<AT, float>) {
            float4 f0 = *(const float4*)(ag + k0);
            float4 f1 = *(const float4*)(ag + k0 + 4);
            float4 f2 = *(const float4*)(ag + k0 + 8);
            float4 f3 = *(const float4*)(ag + k0 + 12);
            a0 = (short8){(short)f2bf(f0.x), (short)f2bf(f0.y), (short)f2bf(f0.z), (short)f2bf(f0.w),
                          (short)f2bf(f1.x), (short)f2bf(f1.y), (short)f2bf(f1.z), (short)f2bf(f1.w)};
            a1 = (short8){(short)f2bf(f2.x), (short)f2bf(f2.y), (short)f2bf(f2.z), (short)f2bf(f2.w),
                          (short)f2bf(f3.x), (short)f2bf(f3.y), (short)f2bf(f3.z), (short)f2bf(f3.w)};
        } else {
            a0 = *(const short8*)(ag + k0);
            a1 = *(const short8*)(ag + k0 + 8);
        }
        short8 b0 = *(const short8*)(bg + k0);
        short8 b1 = *(const short8*)(bg + k0 + 8);
        __syncthreads();   // prior iteration's frag reads done
        *(short8*)&Alds[srow * 40 + skoff]     = a0;
        *(short8*)&Alds[srow * 40 + skoff + 8] = a1;
        *(short8*)&Blds[srow * 40 + skoff]     = b0;
        *(short8*)&Blds[srow * 40 + skoff + 8] = b1;
        __syncthreads();
        short8 af[4], bf[4];
#pragma unroll
        for (int t = 0; t < 4; t++) {
            af[t] = *(const short8*)&Alds[(wm * 64 + t * 16 + m16) * 40 + quad * 8];
            bf[t] = *(const short8*)&Blds[(wn * 64 + t * 16 + m16) * 40 + quad * 8];
        }
#pragma unroll
        for (int i = 0; i < 4; i++)
#pragma unroll
            for (int j = 0; j < 4; j++)
                acc[i][j] = __builtin_amdgcn_mfma_f32_16x16x32_bf16(af[i], bf[j], acc[i][j], 0, 0, 0);
    }

#pragma unroll
    for (int j = 0; j < 4; j++) {
        int col = (int)tn0 + wn * 64 + j * 16 + m16;
        float bsv = bias[col];
#pragma unroll
        for (int i = 0; i < 4; i++) {
            size_t row = tm0 + wm * 64 + i * 16 + quad * 4;
#pragma unroll
            for (int r = 0; r < 4; r++) {
                if constexpr (std::is_same_v<CT, float>)
                    C[(row + r) * (size_t)Nc + col] = acc[i][j][r] + bsv;
                else
                    C[(row + r) * (size_t)Nc + col] = f2bf(acc[i][j][r] + bsv);
            }
        }
    }
}

// ---------------------------------------------------------------------------
// Flash attention per (b,h): Q-tile 64 rows (4 waves x 16), K/V tile 32 rows.
// qh/kh/vh layout: [bb*N + n][h*D + e] (GEMM-natural). Output same layout.
// LDS: K tile row-major (stride 520), V^T staged in two e-halves (stride 40),
// P transpose buffer per wave (stride 40). Total 58,880 B < 64 KB.
// ---------------------------------------------------------------------------
__global__ __launch_bounds__(256, 1)
void attn_kernel(const u16* __restrict__ qh, const u16* __restrict__ kh,
                 const u16* __restrict__ vh, u16* __restrict__ ao)
{
    __shared__ u16 Klds[32 * 520];        // 33,280 B
    __shared__ u16 Vtlds[256 * 40];       // 20,480 B (one e-half: 256 e rows x 32 kv)
    __shared__ u16 Plds[4 * 16 * 40];     //  5,120 B

    const int tid  = threadIdx.x;
    const int lane = tid & 63;
    const int wave = tid >> 6;
    const int m16  = lane & 15;
    const int quad = lane >> 4;
    const int qt = blockIdx.x;     // 16 q-tiles
    const int h  = blockIdx.y;     // 8 heads
    const int bb = blockIdx.z;     // batch within chunk

    // Q fragments (A-operand: A[m=lane&15][k=quad*8+j]) held in registers.
    const int qrow = qt * 64 + wave * 16 + m16;
    const u16* qptr = qh + ((size_t)(bb * N_SZ + qrow)) * HD + h * D_SZ + quad * 8;
    short8 qfrag[16];
#pragma unroll
    for (int kk = 0; kk < 16; kk++)
        qfrag[kk] = *(const short8*)(qptr + kk * 32);

    floatx4 acc[32];                       // O rows quad*4+r, cols ct*16+m16
#pragma unroll
    for (int i = 0; i < 32; i++) acc[i] = (floatx4){0.f, 0.f, 0.f, 0.f};
    float mrow[4], lrow[4];
#pragma unroll
    for (int r = 0; r < 4; r++) { mrow[r] = -3.0e38f; lrow[r] = 0.f; }

    const float scale = 0.04419417382415922f;   // 1/sqrt(512)
    const u16* kbase = kh + ((size_t)(bb * N_SZ)) * HD + h * D_SZ;
    const u16* vbase = vh + ((size_t)(bb * N_SZ)) * HD + h * D_SZ;

    for (int kt = 0; kt < 32; kt++) {
        // ---- global loads into regs ----
        short8 kreg[8], vreg[8];
#pragma unroll
        for (int i = 0; i < 8; i++) {
            int ck = i * 256 + tid;
            int kr = ck >> 6;                       // 0..31
            kreg[i] = *(const short8*)(kbase + (size_t)(kt * 32 + kr) * HD + (ck & 63) * 8);
            int vr  = ck & 31;                      // kv row
            int ech = ck >> 5;                      // e-chunk 0..63
            vreg[i] = *(const short8*)(vbase + (size_t)(kt * 32 + vr) * HD + ech * 8);
        }
        __syncthreads();   // [A] prior-iter LDS reads complete

        // ---- write K tile (b128) + V^T first e-half ----
#pragma unroll
        for (int i = 0; i < 8; i++) {
            int ck = i * 256 + tid;
            *(short8*)&Klds[(ck >> 6) * 520 + (ck & 63) * 8] = kreg[i];
        }
        // V^T: pair lanes (l, l^1) share (ech, rows vr/vr^1) -> one u32 write
#pragma unroll
        for (int i = 0; i < 4; i++) {       // e-half A: ech in [0,32)
            int ck  = i * 256 + tid;
            int vr  = ck & 31;
            int ech = ck >> 5;
#pragma unroll
            for (int j = 0; j < 8; j++) {
                unsigned int mine = (u16)vreg[i][j];
                unsigned int oth  = (unsigned int)__shfl_xor((int)mine, 1, 64);
                unsigned int lo = (lane & 1) ? oth : mine;
                unsigned int hi = (lane & 1) ? mine : oth;
                unsigned int comb = (lo & 0xFFFFu) | (hi << 16);
                if ((lane & 1) == (j >> 2))
                    *(unsigned int*)&Vtlds[(size_t)(ech * 8 + j) * 40 + (vr & ~1)] = comb;
            }
        }
        __syncthreads();   // [B]

        // ---- S = Q K^T (16 rows x 32 cols per wave) ----
        floatx4 s0 = (floatx4){0.f,0.f,0.f,0.f}, s1 = (floatx4){0.f,0.f,0.f,0.f};
#pragma unroll
        for (int kk = 0; kk < 16; kk++) {
            short8 kb0 = *(const short8*)&Klds[(m16) * 520 + kk * 32 + quad * 8];
            short8 kb1 = *(const short8*)&Klds[(16 + m16) * 520 + kk * 32 + quad * 8];
            s0 = __builtin_amdgcn_mfma_f32_16x16x32_bf16(qfrag[kk], kb0, s0, 0, 0, 0);
            s1 = __builtin_amdgcn_mfma_f32_16x16x32_bf16(qfrag[kk], kb1, s1, 0, 0, 0);
        }

        // ---- online softmax (rows quad*4+r; 16-lane butterfly over cols) ----
        float alpha[4];
        u16 pbits[8];
#pragma unroll
        for (int r = 0; r < 4; r++) {
            float a0 = s0[r] * scale, a1 = s1[r] * scale;
            float t = fmaxf(a0, a1);
#pragma unroll
            for (int msk = 1; msk <= 8; msk <<= 1) t = fmaxf(t, __shfl_xor(t, msk, 64));
            float mnew = fmaxf(mrow[r], t);
            alpha[r] = __expf(mrow[r] - mnew);
            mrow[r] = mnew;
            float p0 = __expf(a0 - mnew), p1 = __expf(a1 - mnew);
            float ps = p0 + p1;
#pragma unroll
            for (int msk = 1; msk <= 8; msk <<= 1) ps += __shfl_xor(ps, msk, 64);
            lrow[r] = lrow[r] * alpha[r] + ps;
            pbits[r]     = f2bf(p0);
            pbits[4 + r] = f2bf(p1);
        }
        // write P (C-layout -> LDS row-major for A-layout reread)
#pragma unroll
        for (int r = 0; r < 4; r++) {
            Plds[wave * 640 + (quad * 4 + r) * 40 + m16]      = pbits[r];
            Plds[wave * 640 + (quad * 4 + r) * 40 + 16 + m16] = pbits[4 + r];
        }
        // rescale O
#pragma unroll
        for (int ct = 0; ct < 32; ct++)
#pragma unroll
            for (int r = 0; r < 4; r++) acc[ct][r] *= alpha[r];
        __syncthreads();   // [C]

        // ---- PV first e-half ----
        short8 pf = *(const short8*)&Plds[wave * 640 + m16 * 40 + quad * 8];
#pragma unroll
        for (int ct = 0; ct < 16; ct++) {
            short8 vf = *(const short8*)&Vtlds[(size_t)(ct * 16 + m16) * 40 + quad * 8];
            acc[ct] = __builtin_amdgcn_mfma_f32_16x16x32_bf16(pf, vf, acc[ct], 0, 0, 0);
        }
        __syncthreads();   // [D] e-half A reads done

        // ---- write V^T second e-half, then PV second half ----
#pragma unroll
        for (int i = 4; i < 8; i++) {       // ech in [32,64) -> e' = e-256
            int ck  = i * 256 + tid;
            int vr  = ck & 31;
            int ech = (ck >> 5) - 32;
#pragma unroll
            for (int j = 0; j < 8; j++) {
                unsigned int mine = (u16)vreg[i][j];
                unsigned int oth  = (unsigned int)__shfl_xor((int)mine, 1, 64);
                unsigned int lo = (lane & 1) ? oth : mine;
                unsigned int hi = (lane & 1) ? mine : oth;
                unsigned int comb = (lo & 0xFFFFu) | (hi << 16);
                if ((lane & 1) == (j >> 2))
                    *(unsigned int*)&Vtlds[(size_t)(ech * 8 + j) * 40 + (vr & ~1)] = comb;
            }
        }
        __syncthreads();   // [E]
#pragma unroll
        for (int ct = 16; ct < 32; ct++) {
            short8 vf = *(const short8*)&Vtlds[(size_t)((ct - 16) * 16 + m16) * 40 + quad * 8];
            acc[ct] = __builtin_amdgcn_mfma_f32_16x16x32_bf16(pf, vf, acc[ct], 0, 0, 0);
        }
    }

    // ---- epilogue: O / l, write [bb*N+row][h*D + e] ----
#pragma unroll
    for (int r = 0; r < 4; r++) {
        int row = qt * 64 + wave * 16 + quad * 4 + r;
        float invl = 1.0f / lrow[r];
        size_t obase = ((size_t)(bb * N_SZ + row)) * HD + h * D_SZ;
#pragma unroll
        for (int ct = 0; ct < 32; ct++)
            ao[obase + ct * 16 + m16] = f2bf(acc[ct][r] * invl);
    }
}

// ---------------------------------------------------------------------------
extern "C" void kernel_launch(void* const* d_in, const int* in_sizes, int n_in,
                              void* d_out, int out_size, void* d_ws, size_t ws_size,
                              hipStream_t stream)
{
    const float* kin = (const float*)d_in[0];
    const float* vin = (const float*)d_in[1];
    const float* qin = (const float*)d_in[2];
    const float* Wk  = (const float*)d_in[3];
    const float* bk  = (const float*)d_in[4];
    const float* Wv  = (const float*)d_in[5];
    const float* bv  = (const float*)d_in[6];
    const float* Wq  = (const float*)d_in[7];
    const float* bq  = (const float*)d_in[8];
    const float* Wo  = (const float*)d_in[9];
    const float* bo  = (const float*)d_in[10];
    float* out = (float*)d_out;

    u16* ws = (u16*)d_ws;
    const size_t wEl      = (size_t)H_SZ * D_SZ * D_SZ;  // 2M elems per W
    const size_t permEl   = (size_t)D_SZ * HD;           // 2M elems (Wo permuted)
    const size_t perBatch = (size_t)N_SZ * HD;           // 4M elems per buffer per batch
    const size_t fixedEl  = 3 * wEl + permEl;            // 8M elems
    long long availEl = (long long)(ws_size / 2) - (long long)fixedEl;
    int C = 1;
    if (availEl > 0) {
        long long c = availEl / (long long)(4 * perBatch);
        C = (int)(c < 1 ? 1 : (c > B_SZ ? B_SZ : c));
    }

    u16* wqb = ws;
    u16* wkb = wqb + wEl;
    u16* wvb = wkb + wEl;
    u16* wop = wvb + wEl;
    u16* qh  = wop + permEl;
    u16* khb = qh  + (size_t)C * perBatch;
    u16* vhb = khb + (size_t)C * perBatch;
    u16* ao  = vhb + (size_t)C * perBatch;

    const int cvtBlocks = (int)(wEl / 1024);
    cvt_kernel<<<cvtBlocks, 256, 0, stream>>>(Wq, wqb);
    cvt_kernel<<<cvtBlocks, 256, 0, stream>>>(Wk, wkb);
    cvt_kernel<<<cvtBlocks, 256, 0, stream>>>(Wv, wvb);
    woperm_kernel<<<(int)(permEl / 256), 256, 0, stream>>>(Wo, wop);

    for (int b0 = 0; b0 < B_SZ; b0 += C) {
        int Cc = (B_SZ - b0 < C) ? (B_SZ - b0) : C;
        int M = Cc * N_SZ;
        dim3 gp(M / 128, HD / 128);
        gemm_bt<float, u16><<<gp, 256, 0, stream>>>(qin + (size_t)b0 * N_SZ * D_SZ, wqb, bq, qh,  M, HD, D_SZ);
        gemm_bt<float, u16><<<gp, 256, 0, stream>>>(kin + (size_t)b0 * N_SZ * D_SZ, wkb, bk, khb, M, HD, D_SZ);
        gemm_bt<float, u16><<<gp, 256, 0, stream>>>(vin + (size_t)b0 * N_SZ * D_SZ, wvb, bv, vhb, M, HD, D_SZ);
        attn_kernel<<<dim3(N_SZ / 64, H_SZ, Cc), 256, 0, stream>>>(qh, khb, vhb, ao);
        gemm_bt<u16, float><<<dim3(M / 128, D_SZ / 128), 256, 0, stream>>>(ao, wop, bo,
                                                                           out + (size_t)b0 * N_SZ * D_SZ, M, D_SZ, HD);
    }
}

// Round 3
// 3601.489 us; speedup vs baseline: 1.5996x; 1.5996x over previous
//
#include <hip/hip_runtime.h>
#include <hip/hip_bf16.h>
#include <cstdint>
#include <type_traits>

// (B,N,D,H) = (32,1024,512,8). Inputs/outputs fp32; compute bf16 MFMA.
constexpr int B_SZ = 32;
constexpr int N_SZ = 1024;
constexpr int D_SZ = 512;
constexpr int H_SZ = 8;
constexpr int HD   = H_SZ * D_SZ;   // 4096

typedef __attribute__((ext_vector_type(8))) short short8;   // 8 x bf16
typedef __attribute__((ext_vector_type(4))) float floatx4;  // MFMA acc
typedef unsigned short u16;

static __device__ __forceinline__ u16 f2bf(float f) {
    union { float f; unsigned int i; } c; c.f = f;
    unsigned int x = c.i;
    unsigned int r = x + 0x7FFFu + ((x >> 16) & 1u);  // RNE
    return (u16)(r >> 16);
}

// ---------------------------------------------------------------------------
__global__ void cvt_kernel(const float* __restrict__ src, u16* __restrict__ dst) {
    int idx = (blockIdx.x * 256 + threadIdx.x) * 4;
    float4 v = *(const float4*)(src + idx);
    ushort4 o;
    o.x = f2bf(v.x); o.y = f2bf(v.y); o.z = f2bf(v.z); o.w = f2bf(v.w);
    *(ushort4*)(dst + idx) = o;
}

// Wp[e][h*D+d] = bf16(Wo[e][d*H+h])
__global__ void woperm_kernel(const float* __restrict__ Wo, u16* __restrict__ Wp) {
    int idx = blockIdx.x * 256 + threadIdx.x;      // over 512*4096
    int e = idx >> 12;
    int c = idx & 4095;
    int d  = c & 511;
    int hh = c >> 9;
    Wp[idx] = f2bf(Wo[((size_t)e << 12) + d * H_SZ + hh]);
}

// ---------------------------------------------------------------------------
// GEMM: C = A[M,K] @ W[Nc,K]^T + bias. OM: 0 = bf16 row-major out,
// 1 = f32 row-major out, 2 = bf16 transposed-out vt[(row>>10)*HD+col][n].
// ---------------------------------------------------------------------------
template<typename AT, int OM>
__global__ __launch_bounds__(256, 2)
void gemm_bt(const AT* __restrict__ A, const u16* __restrict__ W,
             const float* __restrict__ bias, void* __restrict__ Cout,
             int M, int Nc, int K)
{
    __shared__ u16 Alds[128 * 40];
    __shared__ u16 Blds[128 * 40];
    const int tid  = threadIdx.x;
    const int lane = tid & 63;
    const int wave = tid >> 6;
    const int wm = wave >> 1, wn = wave & 1;
    const int m16 = lane & 15, quad = lane >> 4;
    const size_t tm0 = (size_t)blockIdx.x * 128;
    const size_t tn0 = (size_t)blockIdx.y * 128;

    floatx4 acc[4][4];
#pragma unroll
    for (int i = 0; i < 4; i++)
#pragma unroll
        for (int j = 0; j < 4; j++) acc[i][j] = (floatx4){0.f, 0.f, 0.f, 0.f};

    const int srow  = tid >> 1;
    const int skoff = (tid & 1) * 16;
    const AT*  ag = A + (tm0 + srow) * (size_t)K + skoff;
    const u16* bg = W + (tn0 + srow) * (size_t)K + skoff;

    for (int k0 = 0; k0 < K; k0 += 32) {
        short8 a0, a1;
        if constexpr (std::is_same_v<AT, float>) {
            float4 f0 = *(const float4*)(ag + k0);
            float4 f1 = *(const float4*)(ag + k0 + 4);
            float4 f2 = *(const float4*)(ag + k0 + 8);
            float4 f3 = *(const float4*)(ag + k0 + 12);
            a0 = (short8){(short)f2bf(f0.x), (short)f2bf(f0.y), (short)f2bf(f0.z), (short)f2bf(f0.w),
                          (short)f2bf(f1.x), (short)f2bf(f1.y), (short)f2bf(f1.z), (short)f2bf(f1.w)};
            a1 = (short8){(short)f2bf(f2.x), (short)f2bf(f2.y), (short)f2bf(f2.z), (short)f2bf(f2.w),
                          (short)f2bf(f3.x), (short)f2bf(f3.y), (short)f2bf(f3.z), (short)f2bf(f3.w)};
        } else {
            a0 = *(const short8*)(ag + k0);
            a1 = *(const short8*)(ag + k0 + 8);
        }
        short8 b0 = *(const short8*)(bg + k0);
        short8 b1 = *(const short8*)(bg + k0 + 8);
        __syncthreads();
        *(short8*)&Alds[srow * 40 + skoff]     = a0;
        *(short8*)&Alds[srow * 40 + skoff + 8] = a1;
        *(short8*)&Blds[srow * 40 + skoff]     = b0;
        *(short8*)&Blds[srow * 40 + skoff + 8] = b1;
        __syncthreads();
        short8 af[4], bf[4];
#pragma unroll
        for (int t = 0; t < 4; t++) {
            af[t] = *(const short8*)&Alds[(wm * 64 + t * 16 + m16) * 40 + quad * 8];
            bf[t] = *(const short8*)&Blds[(wn * 64 + t * 16 + m16) * 40 + quad * 8];
        }
#pragma unroll
        for (int i = 0; i < 4; i++)
#pragma unroll
            for (int j = 0; j < 4; j++)
                acc[i][j] = __builtin_amdgcn_mfma_f32_16x16x32_bf16(af[i], bf[j], acc[i][j], 0, 0, 0);
    }

#pragma unroll
    for (int j = 0; j < 4; j++) {
        int col = (int)tn0 + wn * 64 + j * 16 + m16;
        float bsv = bias[col];
#pragma unroll
        for (int i = 0; i < 4; i++) {
            size_t row = tm0 + wm * 64 + i * 16 + quad * 4;
            if constexpr (OM == 2) {
                // vt[(row>>10)*HD + col][n = row&1023], 4 consecutive n packed
                int cloc = (int)(row >> 10);
                int n0   = (int)(row & 1023);
                ushort4 pk;
                pk.x = f2bf(acc[i][j][0] + bsv);
                pk.y = f2bf(acc[i][j][1] + bsv);
                pk.z = f2bf(acc[i][j][2] + bsv);
                pk.w = f2bf(acc[i][j][3] + bsv);
                u16* vtp = (u16*)Cout;
                *(ushort4*)&vtp[((size_t)cloc * HD + col) * N_SZ + n0] = pk;
            } else {
#pragma unroll
                for (int r = 0; r < 4; r++) {
                    if constexpr (OM == 1)
                        ((float*)Cout)[(row + r) * (size_t)Nc + col] = acc[i][j][r] + bsv;
                    else
                        ((u16*)Cout)[(row + r) * (size_t)Nc + col] = f2bf(acc[i][j][r] + bsv);
                }
            }
        }
    }
}

// ---------------------------------------------------------------------------
// Flash attention per (b,h). Q-tile 64 (4 waves x 16 rows), K/V j-tile 32.
// qh/kh: [bb*N+n][h*D+e]; vt: [bb*HD + h*D+e][n]; out ao: [bb*N+n][h*D+e].
// LDS: K 32x512 XOR-swizzled (32 KB) + V^T 512x32 XOR-swizzled (32 KB) = 64 KB.
// P (4 waves x 16 x 40 u16 = 5 KB) overlays K rows 0..4 (K reads done by then).
// 3 barriers/tile; K(t+1) reg-prefetched during PV(t); V(t) loaded during S(t).
// ---------------------------------------------------------------------------
__global__ __launch_bounds__(256, 2)
void attn_kernel(const u16* __restrict__ qh, const u16* __restrict__ kh,
                 const u16* __restrict__ vt, u16* __restrict__ ao)
{
    __shared__ u16 Klds[32 * 512];        // 32,768 B, swizzled: chunk c' = c ^ (row&7)
    __shared__ u16 Vtlds[512 * 32];       // 32,768 B, swizzled: c' = c ^ (e&3) ^ ((e>>2)&3)
    u16* Plds = Klds;                     // overlay, stride 40, 4x16x40 = 2560 elems

    const int tid  = threadIdx.x;
    const int lane = tid & 63;
    const int wave = tid >> 6;
    const int m16  = lane & 15;
    const int quad = lane >> 4;
    const int qt = blockIdx.x;
    const int h  = blockIdx.y;
    const int bb = blockIdx.z;

    // --- per-lane swizzled LDS addresses (constant across tiles) ---
    // K read: row=m16 (s1: +16), chunk c = kk*4+quad, c' = c ^ (m16&7)
    const int kxor = m16 & 7;
    const int qx8  = (quad ^ (kxor & 3)) * 8;          // elems
    const int kx32 = (kxor & 4) * 8;                   // elems (0 or 32)
    const u16* kaddrE = &Klds[m16 * 512 + qx8 + kx32]; // even kk: + kk*32
    const u16* kaddrO = &Klds[m16 * 512 + qx8 - kx32]; // odd  kk: + kk*32
    // Vt read: row e = ct*16+m16, chunk c = quad, c' = quad^(m16&3)^((m16>>2)&3)
    const int vx8 = (quad ^ (m16 & 3) ^ ((m16 >> 2) & 3)) * 8;
    const u16* vaddr = &Vtlds[m16 * 32 + vx8];          // + ct*512 elems
    // K write: row = i*4+wave, c = lane, c' = lane ^ (row&7)
    // Vt write: e = i*64 + wave*16 + (lane>>2), c = lane&3,
    //           c' = (lane&3)^((lane>>2)&3)^((lane>>4)&3)
    const int ebase = wave * 16 + (lane >> 2);
    const int cw8   = ((lane & 3) ^ ((lane >> 2) & 3) ^ ((lane >> 4) & 3)) * 8;

    // Q fragments in registers (A-operand)
    const int qrow = qt * 64 + wave * 16 + m16;
    const u16* qptr = qh + ((size_t)(bb * N_SZ + qrow)) * HD + h * D_SZ + quad * 8;
    short8 qfrag[16];
#pragma unroll
    for (int kk = 0; kk < 16; kk++)
        qfrag[kk] = *(const short8*)(qptr + kk * 32);

    floatx4 acc[32];
#pragma unroll
    for (int i = 0; i < 32; i++) acc[i] = (floatx4){0.f, 0.f, 0.f, 0.f};
    float mrow[4], lrow[4];
#pragma unroll
    for (int r = 0; r < 4; r++) { mrow[r] = -3.0e38f; lrow[r] = 0.f; }

    const float scale = 0.04419417382415922f;   // 1/sqrt(512)
    const u16* kbase  = kh + ((size_t)(bb * N_SZ)) * HD + h * D_SZ;
    const u16* vtbase = vt + ((size_t)bb * HD + h * D_SZ) * N_SZ;

    // prologue: prefetch K tile 0
    short8 kreg[8];
#pragma unroll
    for (int i = 0; i < 8; i++) {
        int row = i * 4 + wave;
        kreg[i] = *(const short8*)(kbase + (size_t)row * HD + lane * 8);
    }

    for (int kt = 0; kt < 32; kt++) {
        __syncthreads();                              // [A] prev PV reads + P done
        // write K tile from prefetched regs
#pragma unroll
        for (int i = 0; i < 8; i++) {
            int row = i * 4 + wave;
            int cp  = lane ^ (row & 7);
            *(short8*)&Klds[row * 512 + cp * 8] = kreg[i];
        }
        __syncthreads();                              // [B]

        // issue V loads for this tile (consumed after S+softmax)
        short8 vreg[8];
#pragma unroll
        for (int i = 0; i < 8; i++) {
            int e = i * 64 + ebase;
            vreg[i] = *(const short8*)(vtbase + (size_t)e * N_SZ + kt * 32 + (lane & 3) * 8);
        }

        // ---- S = Q K^T ----
        floatx4 s0 = (floatx4){0.f,0.f,0.f,0.f}, s1 = (floatx4){0.f,0.f,0.f,0.f};
#pragma unroll
        for (int kk = 0; kk < 16; kk++) {
            const u16* p = (kk & 1) ? kaddrO : kaddrE;
            short8 kb0 = *(const short8*)(p + kk * 32);
            short8 kb1 = *(const short8*)(p + kk * 32 + 8192);
            s0 = __builtin_amdgcn_mfma_f32_16x16x32_bf16(qfrag[kk], kb0, s0, 0, 0, 0);
            s1 = __builtin_amdgcn_mfma_f32_16x16x32_bf16(qfrag[kk], kb1, s1, 0, 0, 0);
        }

        // ---- online softmax ----
        float alpha[4];
        u16 pbits[8];
#pragma unroll
        for (int r = 0; r < 4; r++) {
            float a0 = s0[r] * scale, a1 = s1[r] * scale;
            float t = fmaxf(a0, a1);
#pragma unroll
            for (int msk = 1; msk <= 8; msk <<= 1) t = fmaxf(t, __shfl_xor(t, msk, 64));
            float mnew = fmaxf(mrow[r], t);
            alpha[r] = __expf(mrow[r] - mnew);
            mrow[r] = mnew;
            float p0 = __expf(a0 - mnew), p1 = __expf(a1 - mnew);
            float ps = p0 + p1;
#pragma unroll
            for (int msk = 1; msk <= 8; msk <<= 1) ps += __shfl_xor(ps, msk, 64);
            lrow[r] = lrow[r] * alpha[r] + ps;
            pbits[r]     = f2bf(p0);
            pbits[4 + r] = f2bf(p1);
        }

        // write V^T tile (waits on vreg; latency hidden by S+softmax)
#pragma unroll
        for (int i = 0; i < 8; i++) {
            int e = i * 64 + ebase;
            *(short8*)&Vtlds[e * 32 + cw8] = vreg[i];
        }
        __syncthreads();                              // [C] S K-reads + Vt writes done

        // P into overlay (wave-local region; K rows 0..4 free now)
#pragma unroll
        for (int r = 0; r < 4; r++) {
            Plds[wave * 640 + (quad * 4 + r) * 40 + m16]      = pbits[r];
            Plds[wave * 640 + (quad * 4 + r) * 40 + 16 + m16] = pbits[4 + r];
        }

        // conditional rescale (skipped when no row max changed)
        float amin = fminf(fminf(alpha[0], alpha[1]), fminf(alpha[2], alpha[3]));
        if (__any(amin < 1.0f)) {
#pragma unroll
            for (int ct = 0; ct < 32; ct++)
#pragma unroll
                for (int r = 0; r < 4; r++) acc[ct][r] *= alpha[r];
        }

        // prefetch K(t+1) during PV
        int ktn = (kt < 31) ? (kt + 1) : kt;
#pragma unroll
        for (int i = 0; i < 8; i++) {
            int row = i * 4 + wave;
            kreg[i] = *(const short8*)(kbase + (size_t)(ktn * 32 + row) * HD + lane * 8);
        }

        // ---- PV ----
        short8 pf = *(const short8*)&Plds[wave * 640 + m16 * 40 + quad * 8];
#pragma unroll
        for (int ct = 0; ct < 32; ct++) {
            short8 vf = *(const short8*)(vaddr + ct * 512);
            acc[ct] = __builtin_amdgcn_mfma_f32_16x16x32_bf16(pf, vf, acc[ct], 0, 0, 0);
        }
    }

    // ---- epilogue ----
#pragma unroll
    for (int r = 0; r < 4; r++) {
        int row = qt * 64 + wave * 16 + quad * 4 + r;
        float invl = 1.0f / lrow[r];
        size_t obase = ((size_t)(bb * N_SZ + row)) * HD + h * D_SZ;
#pragma unroll
        for (int ct = 0; ct < 32; ct++)
            ao[obase + ct * 16 + m16] = f2bf(acc[ct][r] * invl);
    }
}

// ---------------------------------------------------------------------------
extern "C" void kernel_launch(void* const* d_in, const int* in_sizes, int n_in,
                              void* d_out, int out_size, void* d_ws, size_t ws_size,
                              hipStream_t stream)
{
    const float* kin = (const float*)d_in[0];
    const float* vin = (const float*)d_in[1];
    const float* qin = (const float*)d_in[2];
    const float* Wk  = (const float*)d_in[3];
    const float* bk  = (const float*)d_in[4];
    const float* Wv  = (const float*)d_in[5];
    const float* bv  = (const float*)d_in[6];
    const float* Wq  = (const float*)d_in[7];
    const float* bq  = (const float*)d_in[8];
    const float* Wo  = (const float*)d_in[9];
    const float* bo  = (const float*)d_in[10];
    float* out = (float*)d_out;

    u16* ws = (u16*)d_ws;
    const size_t wEl      = (size_t)H_SZ * D_SZ * D_SZ;  // 2M elems per W
    const size_t permEl   = (size_t)D_SZ * HD;           // 2M
    const size_t perBatch = (size_t)N_SZ * HD;           // 4M per buffer per batch
    const size_t fixedEl  = 3 * wEl + permEl;            // 8M
    long long availEl = (long long)(ws_size / 2) - (long long)fixedEl;
    int C = 1;
    if (availEl > 0) {
        long long c = availEl / (long long)(4 * perBatch);
        C = (int)(c < 1 ? 1 : (c > B_SZ ? B_SZ : c));
    }

    u16* wqb = ws;
    u16* wkb = wqb + wEl;
    u16* wvb = wkb + wEl;
    u16* wop = wvb + wEl;
    u16* qh  = wop + permEl;
    u16* khb = qh  + (size_t)C * perBatch;
    u16* vtb = khb + (size_t)C * perBatch;
    u16* ao  = vtb + (size_t)C * perBatch;

    const int cvtBlocks = (int)(wEl / 1024);
    cvt_kernel<<<cvtBlocks, 256, 0, stream>>>(Wq, wqb);
    cvt_kernel<<<cvtBlocks, 256, 0, stream>>>(Wk, wkb);
    cvt_kernel<<<cvtBlocks, 256, 0, stream>>>(Wv, wvb);
    woperm_kernel<<<(int)(permEl / 256), 256, 0, stream>>>(Wo, wop);

    for (int b0 = 0; b0 < B_SZ; b0 += C) {
        int Cc = (B_SZ - b0 < C) ? (B_SZ - b0) : C;
        int M = Cc * N_SZ;
        dim3 gp(M / 128, HD / 128);
        gemm_bt<float, 0><<<gp, 256, 0, stream>>>(qin + (size_t)b0 * N_SZ * D_SZ, wqb, bq, qh,  M, HD, D_SZ);
        gemm_bt<float, 0><<<gp, 256, 0, stream>>>(kin + (size_t)b0 * N_SZ * D_SZ, wkb, bk, khb, M, HD, D_SZ);
        gemm_bt<float, 2><<<gp, 256, 0, stream>>>(vin + (size_t)b0 * N_SZ * D_SZ, wvb, bv, vtb, M, HD, D_SZ);
        attn_kernel<<<dim3(N_SZ / 64, H_SZ, Cc), 256, 0, stream>>>(qh, khb, vtb, ao);
        gemm_bt<u16, 1><<<dim3(M / 128, D_SZ / 128), 256, 0, stream>>>(ao, wop, bo,
                                                                       out + (size_t)b0 * N_SZ * D_SZ, M, D_SZ, HD);
    }
}